// Round 4
// baseline (472.054 us; speedup 1.0000x reference)
//
#include <hip/hip_runtime.h>

// Spiking LIF forward scan, LDS-staged, NORMAL (allocating) global access.
//
// x: (B=128, C=512, T=1024) fp32, t contiguous. beta scalar, Vth per channel.
// Recurrence per (b,c) row is strictly sequential in t (Heaviside spike);
// parallelism = B*C = 65536 rows (structural).
//
// Round-6 A/B: nt -> normal accesses, everything else identical to round 5.
// Rationale: all four nt variants this session (256 B / 512 B / 1 KiB chunks,
// 1- and 2-deep prefetch) sit at 2.6-2.9 TB/s effective while the harness
// fill (normal stores) hits 6.4 TB/s and D2D float4 copy (normal, mixed R+W)
// hits 6.29 TB/s. Granularity scaling moved <5% per doubling => granularity
// disproven. The invariant is nt. Theory: no-allocate/evict-first requests
// ride a capacity-limited bypass path (miss-slot held for full HBM latency,
// no L2-side combining) capping sustained BW ~2.8 TB/s. The prior session's
// nt rationale (avoid evicting harness dirty lines -> parasitic write-backs)
// trades ~130 MB extra traffic (~20 us) against a ~2.3x rate penalty
// (~60 us) -- a bad trade if the bypass theory is right.
//
// Structure (unchanged from round 5): 16 rows/block, CHUNK = 256 floats =
// 1 KiB per row per phase; every load/store instruction is ONE contiguous
// 1 KiB line of ONE row (64 lanes x 16 B). 4 phases over T=1024.
// LDS 16 KB/block -> 10 blocks/CU; pf[16] = 64 VGPRs.
//
// LDS swizzle: element (row, slot s) stored at lds[row*256 + (s ^ row)*4].
// Every DS phase lands 2 lanes/bank per quarter-wave = the free floor
// (round-5 measured SQ_LDS_BANK_CONFLICT = 0).

#define LIF_BC 65536
#define LIF_T  1024
#define CHUNK  256           // floats per row per phase = 1 KiB
#define NP     (LIF_T / CHUNK)  // 4 phases
#define ROWS   16            // rows per block (one wave)
#define JPT    ROWS          // one 1 KiB load/store instr per row per phase

using fvec4 = __attribute__((ext_vector_type(4))) float;

__global__ __launch_bounds__(64) void lif_fwd(
    const float* __restrict__ x,
    const float* __restrict__ beta_p,
    const float* __restrict__ vth_p,
    float* __restrict__ out)
{
    __shared__ float lds[ROWS * CHUNK];  // 16 KB, single buffer

    const int lane = threadIdx.x;        // 0..63
    const int r0   = blockIdx.x * ROWS;  // first (b*C+c) row of this block

    const float beta = beta_p[0];
    const float vth  = vth_p[(r0 + lane) & 511];  // C = 512 (pow2)

    fvec4 pf[JPT];  // one phase of prefetch: 16 rows x 1 KiB -> 64 VGPRs

    // 16 loads; instr j = one contiguous 1 KiB line of row r0+j.
    auto issue_loads = [&](int ph) {
#pragma unroll
        for (int j = 0; j < JPT; ++j) {
            pf[j] = *(const fvec4*)&x[(size_t)(r0 + j) * LIF_T
                                      + (size_t)ph * CHUNK + lane * 4];
        }
    };

    // Drain prefetch regs into LDS (swizzled b128 writes, 2-way free).
    auto write_lds = [&]() {
#pragma unroll
        for (int j = 0; j < JPT; ++j) {
            const int slot = lane ^ j;   // j < 16: permutes slots 0..63
            *(fvec4*)&lds[j * CHUNK + slot * 4] = pf[j];
        }
    };

    float mem = 0.0f, spk = 0.0f;

    // 256 recurrence steps for lane's row (lanes 0..15 active); spikes
    // overwrite LDS in place. Bit-exact fp32 op order vs the reference:
    //   rst = spk*Vth; mem = ((mem*beta) + x) - rst; spk = (mem - Vth) > 0.
    // __f*_rn blocks -ffp-contract FMA fusion (1-ulp drift flips a spike).
    auto compute = [&]() {
        if (lane < ROWS) {
            const int rbase = lane * CHUNK;
            const int sw    = lane;      // row == lane
#pragma unroll
            for (int g = 0; g < CHUNK / 4; ++g) {
                const int slot = g ^ sw;
                fvec4 v = *(fvec4*)&lds[rbase + slot * 4];
#pragma unroll
                for (int e = 0; e < 4; ++e) {
                    float rst = __fmul_rn(spk, vth);
                    mem = __fsub_rn(__fadd_rn(__fmul_rn(mem, beta), v[e]), rst);
                    spk = (__fsub_rn(mem, vth) > 0.0f) ? 1.0f : 0.0f;
                    v[e] = spk;
                }
                *(fvec4*)&lds[rbase + slot * 4] = v;
            }
        }
    };

    // Gather spikes from LDS, store to global: 1 KiB contiguous/instr.
    auto store_tile = [&](int ph) {
#pragma unroll
        for (int j = 0; j < JPT; ++j) {
            const int slot = lane ^ j;
            fvec4 s = *(const fvec4*)&lds[j * CHUNK + slot * 4];
            *(fvec4*)&out[(size_t)(r0 + j) * LIF_T
                          + (size_t)ph * CHUNK + lane * 4] = s;
        }
    };

    // ---- software pipeline: 1 phase of loads in flight during compute ----
    issue_loads(0);
    write_lds();        // waits phase-0 loads (vmcnt issue-ordered), once
    issue_loads(1);     // in flight during compute(0)

    for (int k = 0; k < NP; ++k) {
        compute();                      // recurrence on phase k (in LDS)
        store_tile(k);                  // stores, fire & forget
        if (k + 1 < NP) write_lds();    // regs -> LDS (waits phase-k+1 loads;
                                        //   in-order DS pipe orders after the
                                        //   store gather reads)
        if (k + 2 < NP) issue_loads(k + 2);  // in flight during compute(k+1)
    }
}

extern "C" void kernel_launch(void* const* d_in, const int* in_sizes, int n_in,
                              void* d_out, int out_size, void* d_ws, size_t ws_size,
                              hipStream_t stream) {
    const float* x    = (const float*)d_in[0];  // (B, C, T) fp32
    const float* beta = (const float*)d_in[1];  // scalar
    const float* vth  = (const float*)d_in[2];  // (C,) fp32
    float* out = (float*)d_out;                 // (B, C, T) fp32

    dim3 grid(LIF_BC / ROWS);                   // 4096 one-wave blocks
    lif_fwd<<<grid, 64, 0, stream>>>(x, beta, vth, out);
}

// Round 5
// 447.757 us; speedup vs baseline: 1.0543x; 1.0543x over previous
//
#include <hip/hip_runtime.h>

// Spiking LIF forward scan, double-buffered LDS, store-drain off critical path.
//
// x: (B=128, C=512, T=1024) fp32, t contiguous. beta scalar, Vth per channel.
// Recurrence per (b,c) row is strictly sequential in t; parallelism = 65536 rows.
//
// Round-7 theory: every prior variant (2.4-2.9 TB/s regardless of granularity,
// nt/normal, occupancy, prefetch depth) shared ONE structure: single LDS buffer
// forcing store_tile(k) -> write_lds(k+1). write_lds needs a vmcnt wait for the
// prefetch loads; vmcnt is issue-ordered and the compiler emits a conservative
// vmcnt(0), which ALSO drains the 16 just-issued global stores -> a full store
// round-trip on the critical path of EVERY phase of EVERY wave, with zero VMEM
// in flight during the stall. The 6.4 TB/s fill kernel never waits on stores.
//
// Fix: DOUBLE-buffer LDS and put write_lds(next) BEFORE store_tile(cur). At
// every vmcnt wait point the newest outstanding stores are >= 1 compute phase
// (~2.5K cyc) old -> complete; stores become genuinely fire-and-forget.
// CHUNK 256 -> 128 keeps 2 x 8 KB = 16 KB/block -> 10 blocks/CU (occupancy
// unchanged vs round 6; 512 B chunks cost <=5% per the granularity ladder).
//
// Also: recurrence critical path 20 -> 16 cyc/step. Carry rst in {+0, vth}
// selected by cndmask instead of rst = spk*vth (fmul after cndmask). Bit-exact:
// 0.0f*vth == +0.0f, 1.0f*vth == vth; mem op order unchanged; spike value and
// the compare (on the explicit fsub result) unchanged.
//
// nt loads/stores kept (empirically best: 146 vs 166 us normal; WRITE_SIZE was
// ideal either way in round 6).
//
// LDS swizzle: slot = l_t ^ (row & 15) (XOR of low 4 bits, bijective per row);
// all DS phases land on the measured-zero-conflict XOR family.

#define LIF_BC 65536
#define LIF_T  1024
#define CHUNK  128              // floats per row per phase = 512 B
#define NP     (LIF_T / CHUNK)  // 8 phases
#define ROWS   16               // rows per block (one wave)
#define JPT    8                // load/store instrs per phase (2 rows x 512 B each)

using fvec4 = __attribute__((ext_vector_type(4))) float;

__global__ __launch_bounds__(64) void lif_fwd(
    const float* __restrict__ x,
    const float* __restrict__ beta_p,
    const float* __restrict__ vth_p,
    float* __restrict__ out)
{
    __shared__ float ldsA[ROWS * CHUNK];  // 8 KB
    __shared__ float ldsB[ROWS * CHUNK];  // 8 KB

    const int lane = threadIdx.x;        // 0..63
    const int r0   = blockIdx.x * ROWS;  // first (b*C+c) row of this block

    const float beta = beta_p[0];
    const float vth  = vth_p[(r0 + lane) & 511];  // C = 512 (pow2)

    // 2 rows per instr: lanes 0..31 -> row 2j, lanes 32..63 -> row 2j+1
    const int l_row2 = lane >> 5;  // 0..1
    const int l_t    = lane & 31;  // 4-float slot within row (0..31)

    fvec4 pf[JPT];  // one phase of prefetch: 16 rows x 512 B -> 32 VGPRs

    auto issue_loads = [&](int ph) {
#pragma unroll
        for (int j = 0; j < JPT; ++j) {
            const int row = 2 * j + l_row2;
            pf[j] = __builtin_nontemporal_load(
                (const fvec4*)&x[(size_t)(r0 + row) * LIF_T
                                 + (size_t)ph * CHUNK + l_t * 4]);
        }
    };

    auto write_lds = [&](float* buf) {
#pragma unroll
        for (int j = 0; j < JPT; ++j) {
            const int row  = 2 * j + l_row2;
            const int slot = l_t ^ (row & 15);
            *(fvec4*)&buf[row * CHUNK + slot * 4] = pf[j];
        }
    };

    float mem = 0.0f, rst = 0.0f;   // rst in {+0, vth} carries the spike state

    // 128 recurrence steps per phase (lanes 0..15 active, one row each).
    // Bit-exact vs reference: rst == spk*vth (0*vth=+0, 1*vth=vth);
    //   mem = ((mem*beta) + x) - rst; spike test on the explicit fsub result.
    // __f*_rn blocks -ffp-contract FMA fusion (1-ulp drift flips a spike).
    auto compute = [&](float* buf) {
        if (lane < ROWS) {
            const int rbase = lane * CHUNK;
            const int sw    = lane & 15;
#pragma unroll
            for (int g = 0; g < CHUNK / 4; ++g) {
                const int slot = g ^ sw;
                fvec4 v = *(fvec4*)&buf[rbase + slot * 4];
#pragma unroll
                for (int e = 0; e < 4; ++e) {
                    float a = __fadd_rn(__fmul_rn(mem, beta), v[e]);
                    mem = __fsub_rn(a, rst);
                    const bool s = __fsub_rn(mem, vth) > 0.0f;
                    rst  = s ? vth : 0.0f;   // next step's reset (off mem path)
                    v[e] = s ? 1.0f : 0.0f;  // recorded spike (off critical path)
                }
                *(fvec4*)&buf[rbase + slot * 4] = v;
            }
        }
    };

    auto store_tile = [&](const float* buf, int ph) {
#pragma unroll
        for (int j = 0; j < JPT; ++j) {
            const int row  = 2 * j + l_row2;
            const int slot = l_t ^ (row & 15);
            fvec4 s = *(const fvec4*)&buf[row * CHUNK + slot * 4];
            __builtin_nontemporal_store(
                s, (fvec4*)&out[(size_t)(r0 + row) * LIF_T
                                + (size_t)ph * CHUNK + l_t * 4]);
        }
    };

    // ---- pipeline: write_lds BEFORE store_tile; stores never waited fresh ----
    issue_loads(0);
    write_lds(ldsA);     // vmcnt waits tile-0 loads only (nothing else in flight)
    issue_loads(1);

    for (int k = 0; k < NP; k += 2) {
        // even phase k (A side)
        compute(ldsA);
        write_lds(ldsB);                    // waits loads(k+1); newest stores are
                                            //   1 compute phase old -> complete
        if (k + 2 < NP) issue_loads(k + 2);
        store_tile(ldsA, k);                // fire & forget
        // odd phase k+1 (B side)
        compute(ldsB);
        if (k + 2 < NP) write_lds(ldsA);    // waits loads(k+2)
        if (k + 3 < NP) issue_loads(k + 3);
        store_tile(ldsB, k + 1);
    }
}

extern "C" void kernel_launch(void* const* d_in, const int* in_sizes, int n_in,
                              void* d_out, int out_size, void* d_ws, size_t ws_size,
                              hipStream_t stream) {
    const float* x    = (const float*)d_in[0];  // (B, C, T) fp32
    const float* beta = (const float*)d_in[1];  // scalar
    const float* vth  = (const float*)d_in[2];  // (C,) fp32
    float* out = (float*)d_out;                 // (B, C, T) fp32

    dim3 grid(LIF_BC / ROWS);                   // 4096 one-wave blocks
    lif_fwd<<<grid, 64, 0, stream>>>(x, beta, vth, out);
}

// Round 6
// 445.214 us; speedup vs baseline: 1.0603x; 1.0057x over previous
//
#include <hip/hip_runtime.h>

// Spiking LIF forward scan, double-buffered LDS + 2-deep register prefetch.
//
// x: (B=128, C=512, T=1024) fp32, t contiguous. beta scalar, Vth per channel.
// Recurrence per (b,c) row is strictly sequential in t; parallelism = 65536 rows.
//
// Session ledger:
//   granularity 256B->1KB: ~10% total. nt > normal (146 vs 166 us).
//   occupancy 4->10 blocks/CU: ~nil. store-drain reorder (R5): -13..18%,
//   the biggest lever => kernel is WAIT-bound, all pipes idle
//   (VALUBusy 23%, DS ~20us, HBM floor 62-85us vs ~130us measured).
//
// Round-8 theory: the last wait on the critical path is write_lds(k+1)
// blocking on loads issued only ~1 compute phase (~2K cyc) earlier. Unloaded
// HBM latency (~900 cyc) would be covered, but LOADED latency under queueing
// (bursty 8-instr packets from 2560 waves, 4 KB-strided) plausibly runs
// 2-5K cyc => a partial stall every phase of every wave. Fix: TWO prefetch
// buffers (pf0 = even phases, pf1 = odd); loads issue ~2 compute phases
// (~4-5K cyc) ahead of their wait. R1's 2-deep attempt was voided by a
// 256-VGPR spill; at CHUNK=128 the pair costs 64 VGPRs total (~116 w/ addr,
// no spill). Everything else identical to R5 (clean A/B on depth):
// dbuf LDS 2x8 KB -> 10 blocks/CU (LDS-capped, unchanged), write-before-
// store order, nt accesses, cndmask recurrence, XOR swizzle (0 conflicts).

#define LIF_BC 65536
#define LIF_T  1024
#define CHUNK  128              // floats per row per phase = 512 B
#define NP     (LIF_T / CHUNK)  // 8 phases
#define ROWS   16               // rows per block (one wave)
#define JPT    8                // load/store instrs per phase (2 rows x 512 B)

using fvec4 = __attribute__((ext_vector_type(4))) float;

__global__ __launch_bounds__(64) void lif_fwd(
    const float* __restrict__ x,
    const float* __restrict__ beta_p,
    const float* __restrict__ vth_p,
    float* __restrict__ out)
{
    __shared__ float ldsA[ROWS * CHUNK];  // 8 KB
    __shared__ float ldsB[ROWS * CHUNK];  // 8 KB

    const int lane = threadIdx.x;        // 0..63
    const int r0   = blockIdx.x * ROWS;  // first (b*C+c) row of this block

    const float beta = beta_p[0];
    const float vth  = vth_p[(r0 + lane) & 511];  // C = 512 (pow2)

    // 2 rows per instr: lanes 0..31 -> row 2j, lanes 32..63 -> row 2j+1
    const int l_row2 = lane >> 5;  // 0..1
    const int l_t    = lane & 31;  // 4-float slot within row (0..31)

    fvec4 pf0[JPT], pf1[JPT];  // 2-deep prefetch: 64 VGPRs total

    auto issue_loads = [&](fvec4 (&pf)[JPT], int ph) {
#pragma unroll
        for (int j = 0; j < JPT; ++j) {
            const int row = 2 * j + l_row2;
            pf[j] = __builtin_nontemporal_load(
                (const fvec4*)&x[(size_t)(r0 + row) * LIF_T
                                 + (size_t)ph * CHUNK + l_t * 4]);
        }
    };

    auto write_lds = [&](float* buf, fvec4 (&pf)[JPT]) {
#pragma unroll
        for (int j = 0; j < JPT; ++j) {
            const int row  = 2 * j + l_row2;
            const int slot = l_t ^ (row & 15);
            *(fvec4*)&buf[row * CHUNK + slot * 4] = pf[j];
        }
    };

    float mem = 0.0f, rst = 0.0f;   // rst in {+0, vth} carries the spike state

    // 128 recurrence steps per phase (lanes 0..15 active, one row each).
    // Bit-exact vs reference: rst == spk*vth (0*vth=+0, 1*vth=vth);
    //   mem = ((mem*beta) + x) - rst; spike test on the explicit fsub result.
    // __f*_rn blocks -ffp-contract FMA fusion (1-ulp drift flips a spike).
    auto compute = [&](float* buf) {
        if (lane < ROWS) {
            const int rbase = lane * CHUNK;
            const int sw    = lane & 15;
#pragma unroll
            for (int g = 0; g < CHUNK / 4; ++g) {
                const int slot = g ^ sw;
                fvec4 v = *(fvec4*)&buf[rbase + slot * 4];
#pragma unroll
                for (int e = 0; e < 4; ++e) {
                    float a = __fadd_rn(__fmul_rn(mem, beta), v[e]);
                    mem = __fsub_rn(a, rst);
                    const bool s = __fsub_rn(mem, vth) > 0.0f;
                    rst  = s ? vth : 0.0f;   // next step's reset (off mem path)
                    v[e] = s ? 1.0f : 0.0f;  // recorded spike (off critical path)
                }
                *(fvec4*)&buf[rbase + slot * 4] = v;
            }
        }
    };

    auto store_tile = [&](const float* buf, int ph) {
#pragma unroll
        for (int j = 0; j < JPT; ++j) {
            const int row  = 2 * j + l_row2;
            const int slot = l_t ^ (row & 15);
            fvec4 s = *(const fvec4*)&buf[row * CHUNK + slot * 4];
            __builtin_nontemporal_store(
                s, (fvec4*)&out[(size_t)(r0 + row) * LIF_T
                                + (size_t)ph * CHUNK + l_t * 4]);
        }
    };

    // ---- pipeline: loads issued ~2 compute phases before their wait -------
    issue_loads(pf0, 0);
    issue_loads(pf1, 1);
    write_lds(ldsA, pf0);    // waits loads(0) only
    issue_loads(pf0, 2);     // in flight across compute(0)+compute(1)

    for (int k = 0; k < NP; k += 2) {
        // even phase k (A / pf0 side)
        compute(ldsA);
        write_lds(ldsB, pf1);                     // waits loads(k+1), issued
                                                  //   ~2 computes ago
        if (k + 3 < NP) issue_loads(pf1, k + 3);  // lead: 2 computes
        store_tile(ldsA, k);                      // fire & forget (nt)
        // odd phase k+1 (B / pf1 side)
        compute(ldsB);
        if (k + 2 < NP) write_lds(ldsA, pf0);     // waits loads(k+2)
        if (k + 4 < NP) issue_loads(pf0, k + 4);
        store_tile(ldsB, k + 1);
    }
}

extern "C" void kernel_launch(void* const* d_in, const int* in_sizes, int n_in,
                              void* d_out, int out_size, void* d_ws, size_t ws_size,
                              hipStream_t stream) {
    const float* x    = (const float*)d_in[0];  // (B, C, T) fp32
    const float* beta = (const float*)d_in[1];  // scalar
    const float* vth  = (const float*)d_in[2];  // (C,) fp32
    float* out = (float*)d_out;                 // (B, C, T) fp32

    dim3 grid(LIF_BC / ROWS);                   // 4096 one-wave blocks
    lif_fwd<<<grid, 64, 0, stream>>>(x, beta, vth, out);
}